// Round 3
// baseline (52.785 us; speedup 1.0000x reference)
//
#include <hip/hip_runtime.h>
#include <hip/hip_bf16.h>
#include <stdint.h>

// costh[B,CK] = (x/||x||_row) @ (W/||W||_col),  x:[B,D] f32, W:[D,CK] f32
// B=512, D=512, CK=5994*3=17982. Output f32.
// Two kernels: xnorm (x -> normalized bf16 granule tiles) + gemm_fused
// (W staged f32->bf16 in-kernel, column sumsq fused, winv applied in epilogue).

#define D_DIM 512
#define BM 128
#define BN 128
#define NSTEPS 16                  // K-steps of 32
#define TILE_BYTES (64 * BM * 16)  // An per-mtile: 64 granules x 128 rows x 16B = 128KB

typedef __bf16 bf16x8 __attribute__((ext_vector_type(8)));
typedef float f32x4 __attribute__((ext_vector_type(4)));
typedef unsigned short ushort8 __attribute__((ext_vector_type(8)));

__device__ __forceinline__ unsigned short f2bf(float f) {
  union { float f; unsigned int u; } v; v.f = f;
  unsigned int u = v.u;
  u += 0x7fffu + ((u >> 16) & 1u);   // RNE
  return (unsigned short)(u >> 16);
}

__device__ __forceinline__ void load_lds16(const void* g, void* l) {
  __builtin_amdgcn_global_load_lds(
      (__attribute__((address_space(1))) void*)(g),
      (__attribute__((address_space(3))) void*)(l), 16, 0, 0);
}

// ---------------- kernel 1: x row norms -> An tiled bf16 (normalized) ----------------
// grid: B/4 blocks x 256 threads; one wave per row, lane = granule.
__global__ void xnorm_kernel(const float* __restrict__ x, unsigned short* __restrict__ An) {
  const int t = threadIdx.x;
  const int w = t >> 6, lane = t & 63;
  const int m = blockIdx.x * 4 + w;
  const float* xr = x + (size_t)m * D_DIM + lane * 8;
  float4 a = *(const float4*)(xr);
  float4 b = *(const float4*)(xr + 4);
  float s = a.x * a.x + a.y * a.y + a.z * a.z + a.w * a.w +
            b.x * b.x + b.y * b.y + b.z * b.z + b.w * b.w;
#pragma unroll
  for (int off = 32; off; off >>= 1) s += __shfl_xor(s, off, 64);
  const float inv = 1.f / fmaxf(sqrtf(s), 1e-8f);
  ushort4 o0, o1;
  o0.x = f2bf(a.x * inv); o0.y = f2bf(a.y * inv); o0.z = f2bf(a.z * inv); o0.w = f2bf(a.w * inv);
  o1.x = f2bf(b.x * inv); o1.y = f2bf(b.y * inv); o1.z = f2bf(b.z * inv); o1.w = f2bf(b.w * inv);
  const int mtile = m >> 7, r = m & 127;
  unsigned short* dst = An + (size_t)mtile * (TILE_BYTES / 2) + (size_t)lane * (BM * 8) + r * 8;
  *(ushort4*)dst = o0;
  *(ushort4*)(dst + 4) = o1;
}

// ---------------- kernel 2: fused GEMM ----------------
// grid (ntiles, mtiles) x 256 threads (4 waves). 128x128 tile, BK=32, dbuf LDS,
// one raw barrier per K-step with counted vmcnt. W read f32 in-kernel.
__global__ __launch_bounds__(256, 2) void gemm_fused(const unsigned short* __restrict__ An,
                                                     const float* __restrict__ W,
                                                     float* __restrict__ out, int CK) {
  __shared__ __attribute__((aligned(16))) unsigned char lds[32768];
  // bufA: [0,8K),[8K,16K)   bufB: [16K,24K),[24K,32K)
  const int ntile = blockIdx.x, mtile = blockIdx.y;
  const int t = threadIdx.x;
  const int lane = t & 63, w = t >> 6;
  const int wm = w >> 1, wn = w & 1;          // wave -> 64x64 quadrant
  const int lrow = lane & 15;
  const int kg = lane >> 4;                   // k-granule for fragment reads

  const unsigned char* srcA = (const unsigned char*)An + (size_t)mtile * TILE_BYTES;
  const int n0 = ntile * BN;
  const int nn = t & 127;                     // staged column (local)
  const int h = t >> 7;                       // granules h, h+2
  const int ncl = (n0 + nn < CK) ? nn : (CK - 1 - n0);  // clamp for tail tile
  const float* __restrict__ Wcol = W + n0 + ncl;

  f32x4 acc[4][4] = {};
  float wsq = 0.f;
  float r[16];

  // prologue: issue B(0) reg loads, then A_lds(0) -> bufA0
#pragma unroll
  for (int l = 0; l < 16; ++l)
    r[l] = Wcol[(size_t)((h + 2 * (l >> 3)) * 8 + (l & 7)) * CK];
#pragma unroll
  for (int c = 0; c < 2; ++c) {
    const int off = w * 2048 + c * 1024;
    load_lds16(srcA + off + lane * 16, lds + off);
  }

#pragma unroll 2
  for (int kt = 0; kt < NSTEPS; ++kt) {
    const int cur = kt & 1;
    unsigned char* bufA = lds + cur * 8192;
    unsigned char* bufB = lds + 16384 + cur * 8192;

    // step1+2: convert B(kt), accumulate column sumsq, ds_write granules
#pragma unroll
    for (int idx = 0; idx < 2; ++idx) {
      bf16x8 v;
#pragma unroll
      for (int j = 0; j < 8; ++j) {
        const float f = r[idx * 8 + j];
        wsq += f * f;
        v[j] = (__bf16)f;
      }
      *(bf16x8*)(bufB + (h + 2 * idx) * 2048 + nn * 16) = v;
    }

    // step3: issue B(kt+1) reg loads (regs free after cvt)
    if (kt + 1 < NSTEPS) {
#pragma unroll
      for (int l = 0; l < 16; ++l)
        r[l] = Wcol[(size_t)((kt + 1) * 32 + (h + 2 * (l >> 3)) * 8 + (l & 7)) * CK];
    }

    // step5: counted waits + raw barrier (A_lds(kt) retired; my ds_writes visible)
    __builtin_amdgcn_sched_barrier(0);
    if (kt + 1 < NSTEPS) {
      asm volatile("s_waitcnt vmcnt(16)" ::: "memory");  // outstanding: A_lds(kt)=2 + B(kt+1)=16
    } else {
      asm volatile("s_waitcnt vmcnt(0)" ::: "memory");
    }
    asm volatile("s_waitcnt lgkmcnt(0)" ::: "memory");
    __builtin_amdgcn_s_barrier();
    __builtin_amdgcn_sched_barrier(0);

    // step6: issue A_lds(kt+1) into the other buffer (safe: all waves drained lgkm pre-barrier)
    if (kt + 1 < NSTEPS) {
      unsigned char* bufAn = lds + (cur ^ 1) * 8192;
      const size_t koff = (size_t)(kt + 1) * 8192;
#pragma unroll
      for (int c = 0; c < 2; ++c) {
        const int off = w * 2048 + c * 1024;
        load_lds16(srcA + koff + off + lane * 16, bufAn + off);
      }
    }

    // step7: fragment reads + MFMA
    bf16x8 afrag[4], bfrag[4];
#pragma unroll
    for (int i = 0; i < 4; ++i) {
      afrag[i] = *(const bf16x8*)(bufA + kg * 2048 + (wm * 64 + i * 16 + lrow) * 16);
      bfrag[i] = *(const bf16x8*)(bufB + kg * 2048 + (wn * 64 + i * 16 + lrow) * 16);
    }
#pragma unroll
    for (int i = 0; i < 4; ++i)
#pragma unroll
      for (int j = 0; j < 4; ++j)
        acc[i][j] = __builtin_amdgcn_mfma_f32_16x16x32_bf16(afrag[i], bfrag[j], acc[i][j], 0, 0, 0);
  }

  // ---- winv reduction (red/winv live in bufA0 region, disjoint from last iter's bufA1/bufB1) ----
  float* red = (float*)lds;              // 256 f32
  float* winv = (float*)(lds + 2048);    // 128 f32
  red[t] = wsq;
  __syncthreads();
  if (t < 128) {
    const float s = red[t] + red[t + 128];
    winv[t] = 1.f / fmaxf(sqrtf(s), 1e-8f);
  }
  __syncthreads();

  // ---- epilogue: C layout col=lane&15, row=(lane>>4)*4+reg ----
#pragma unroll
  for (int j = 0; j < 4; ++j) {
    const int cl = wn * 64 + j * 16 + lrow;
    const int col = n0 + cl;
    if (col < CK) {
      const float wv = winv[cl];
#pragma unroll
      for (int i = 0; i < 4; ++i) {
#pragma unroll
        for (int jj = 0; jj < 4; ++jj) {
          const int row = mtile * BM + wm * 64 + i * 16 + kg * 4 + jj;
          out[(size_t)row * CK + col] = acc[i][j][jj] * wv;
        }
      }
    }
  }
}

extern "C" void kernel_launch(void* const* d_in, const int* in_sizes, int n_in,
                              void* d_out, int out_size, void* d_ws, size_t ws_size,
                              hipStream_t stream) {
  const float* x = (const float*)d_in[0];
  const float* W = (const float*)d_in[1];
  float* out = (float*)d_out;
  const int Bn = in_sizes[0] / D_DIM;     // 512
  const int CK = in_sizes[1] / D_DIM;     // 17982
  const int ntiles = (CK + BN - 1) / BN;  // 141
  const int mtiles = Bn / BM;             // 4

  unsigned short* An = (unsigned short*)d_ws;  // 512 KB

  hipLaunchKernelGGL(xnorm_kernel, dim3(Bn / 4), dim3(256), 0, stream, x, An);
  hipLaunchKernelGGL(gemm_fused, dim3(ntiles, mtiles), dim3(256), 0, stream, An, W, out, CK);
}

// Round 4
// 41.574 us; speedup vs baseline: 1.2697x; 1.2697x over previous
//
#include <hip/hip_runtime.h>
#include <hip/hip_bf16.h>
#include <stdint.h>

// costh[B,CK] = (x/||x||_row) @ (W/||W||_col),  x:[B,D] f32, W:[D,CK] f32
// B=512, D=512, CK=5994*3=17982. Output f32.
// Kernel 1 (prep): W -> Wt bf16 granule tiles (register-only transpose, coalesced
//   both sides) + per-column partial sumsq; x -> An normalized bf16 granule tiles
//   (extra blocks, runs concurrently).
// Kernel 2 (gemm): 128x128 tile, BK=64, 2-phase double-buffered LDS via
//   global_load_lds, one barrier per K-iter, winv folded into epilogue.

#define D_DIM 512
#define BM 128
#define BN 128
#define BK 64
#define KITERS (D_DIM / BK)        // 8
#define TILE_BYTES (64 * BM * 16)  // 131072 B per 128-col tile (64 granules x 128 x 16B)

typedef __bf16 bf16x8 __attribute__((ext_vector_type(8)));
typedef float f32x4 __attribute__((ext_vector_type(4)));

__device__ __forceinline__ unsigned short f2bf(float f) {
  union { float f; unsigned int u; } v; v.f = f;
  unsigned int u = v.u;
  u += 0x7fffu + ((u >> 16) & 1u);   // RNE
  return (unsigned short)(u >> 16);
}

__device__ __forceinline__ void load_lds16(const void* g, void* l) {
  __builtin_amdgcn_global_load_lds(
      (__attribute__((address_space(1))) void*)(g),
      (__attribute__((address_space(3))) void*)(l), 16, 0, 0);
}

// ---------------- kernel 1: prep (wtrans blocks + xnorm blocks) ----------------
// wtrans blocks: b < ntiles*8. 256 threads: cq=t&31 (4 cols), dr=t>>5 (granule).
// Thread loads 8 coalesced float4 rows (one granule x 4 cols), assembles 4
// granules in registers, stores 64B contiguous. Column sumsq reduced via 4KB LDS.
__global__ void prep_kernel(const float* __restrict__ x, const float* __restrict__ W,
                            unsigned short* __restrict__ An, unsigned short* __restrict__ Wt,
                            float* __restrict__ partial, int CK, int NT128, int nWtBlocks) {
  const int b = blockIdx.x;
  const int t = threadIdx.x;
  if (b < nWtBlocks) {
    __shared__ float red[8 * 128];
    const int ntile = b >> 3, gb = b & 7;
    const int cq = t & 31, dr = t >> 5;
    const int n0 = ntile * BN;
    const int nb = n0 + cq * 4;
    const int g = gb * 8 + dr;               // granule (k/8)
    float ss0 = 0.f, ss1 = 0.f, ss2 = 0.f, ss3 = 0.f;
    unsigned int gr[4][4];                   // [col][pair] packed bf16x2
    if (n0 + BN <= CK) {
#pragma unroll
      for (int i = 0; i < 8; i += 2) {
        float4 v0 = *(const float4*)(W + (size_t)(g * 8 + i) * CK + nb);
        float4 v1 = *(const float4*)(W + (size_t)(g * 8 + i + 1) * CK + nb);
        ss0 += v0.x * v0.x + v1.x * v1.x; ss1 += v0.y * v0.y + v1.y * v1.y;
        ss2 += v0.z * v0.z + v1.z * v1.z; ss3 += v0.w * v0.w + v1.w * v1.w;
        gr[0][i >> 1] = (unsigned int)f2bf(v0.x) | ((unsigned int)f2bf(v1.x) << 16);
        gr[1][i >> 1] = (unsigned int)f2bf(v0.y) | ((unsigned int)f2bf(v1.y) << 16);
        gr[2][i >> 1] = (unsigned int)f2bf(v0.z) | ((unsigned int)f2bf(v1.z) << 16);
        gr[3][i >> 1] = (unsigned int)f2bf(v0.w) | ((unsigned int)f2bf(v1.w) << 16);
      }
    } else {
      float acc_ss[4] = {0.f, 0.f, 0.f, 0.f};
#pragma unroll
      for (int i = 0; i < 8; i += 2) {
#pragma unroll
        for (int e = 0; e < 4; ++e) {
          const int n = nb + e;
          const float f0 = (n < CK) ? W[(size_t)(g * 8 + i) * CK + n] : 0.f;
          const float f1 = (n < CK) ? W[(size_t)(g * 8 + i + 1) * CK + n] : 0.f;
          acc_ss[e] += f0 * f0 + f1 * f1;
          gr[e][i >> 1] = (unsigned int)f2bf(f0) | ((unsigned int)f2bf(f1) << 16);
        }
      }
      ss0 = acc_ss[0]; ss1 = acc_ss[1]; ss2 = acc_ss[2]; ss3 = acc_ss[3];
    }
    // store 4 granules (16B each, 64B contiguous per thread, coalesced per wave)
    unsigned short* dst = Wt + (size_t)ntile * (TILE_BYTES / 2) + (size_t)g * (BM * 8) + (size_t)cq * 32;
#pragma unroll
    for (int e = 0; e < 4; ++e) {
      uint4 o; o.x = gr[e][0]; o.y = gr[e][1]; o.z = gr[e][2]; o.w = gr[e][3];
      *(uint4*)(dst + e * 8) = o;
    }
    // column sumsq partial
    *(float4*)(&red[dr * 128 + cq * 4]) = make_float4(ss0, ss1, ss2, ss3);
    __syncthreads();
    if (t < 128) {
      float s = 0.f;
#pragma unroll
      for (int k = 0; k < 8; ++k) s += red[k * 128 + t];
      partial[(size_t)gb * NT128 + n0 + t] = s;
    }
  } else {
    // xnorm: 4 rows per block, one wave per row
    const int w = t >> 6, lane = t & 63;
    const int m = (b - nWtBlocks) * 4 + w;
    const float* xr = x + (size_t)m * D_DIM + lane * 8;
    float4 a = *(const float4*)(xr);
    float4 c = *(const float4*)(xr + 4);
    float s = a.x * a.x + a.y * a.y + a.z * a.z + a.w * a.w +
              c.x * c.x + c.y * c.y + c.z * c.z + c.w * c.w;
#pragma unroll
    for (int off = 32; off; off >>= 1) s += __shfl_xor(s, off, 64);
    const float inv = 1.f / fmaxf(sqrtf(s), 1e-8f);
    ushort4 o0, o1;
    o0.x = f2bf(a.x * inv); o0.y = f2bf(a.y * inv); o0.z = f2bf(a.z * inv); o0.w = f2bf(a.w * inv);
    o1.x = f2bf(c.x * inv); o1.y = f2bf(c.y * inv); o1.z = f2bf(c.z * inv); o1.w = f2bf(c.w * inv);
    const int mtile = m >> 7, r = m & 127;
    unsigned short* dst = An + (size_t)mtile * (TILE_BYTES / 2) + (size_t)lane * (BM * 8) + r * 8;
    *(ushort4*)dst = o0;
    *(ushort4*)(dst + 4) = o1;
  }
}

// ---------------- kernel 2: GEMM, BK=64, 2-phase dbuf, XCD swizzle ----------------
__global__ __launch_bounds__(256, 2) void gemm_kernel(const unsigned short* __restrict__ An,
                                                      const unsigned short* __restrict__ Wt,
                                                      const float* __restrict__ partial,
                                                      float* __restrict__ out, int CK, int NT128) {
  __shared__ __attribute__((aligned(16))) unsigned char lds[65536];
  // buf0: A [0,16K) B [16K,32K); buf1: A [32K,48K) B [48K,64K)
  const int total = gridDim.x;
  const int q = total >> 3, rr = total & 7;
  const int lin = blockIdx.x;
  const int xcd = lin & 7, idx = lin >> 3;
  const int wg = (xcd < rr) ? xcd * (q + 1) + idx : rr * (q + 1) + (xcd - rr) * q + idx;
  const int ntile = wg >> 2, mtile = wg & 3;

  const int t = threadIdx.x;
  const int lane = t & 63, w = t >> 6;
  const int wm = w >> 1, wn = w & 1;          // wave -> 64x64 quadrant
  const int lrow = lane & 15;
  const int kg = lane >> 4;                   // k-granule slot 0..3

  const unsigned char* srcA = (const unsigned char*)An + (size_t)mtile * TILE_BYTES;
  const unsigned char* srcB = (const unsigned char*)Wt + (size_t)ntile * TILE_BYTES;
  const int n0 = ntile * BN;

  f32x4 acc[4][4] = {};

  // stage(kt) -> buffer sel: 16KB A + 16KB B, 8 x load_lds16 per thread
#define STAGE(kt, sel)                                                        \
  {                                                                           \
    const size_t koff = (size_t)(kt) * 16384;                                 \
    unsigned char* bA = lds + (sel) * 32768;                                  \
    unsigned char* bB = bA + 16384;                                           \
    _Pragma("unroll")                                                         \
    for (int c = 0; c < 4; ++c) {                                             \
      const int off = w * 4096 + c * 1024;                                    \
      load_lds16(srcA + koff + off + lane * 16, bA + off);                    \
    }                                                                         \
    _Pragma("unroll")                                                         \
    for (int c = 0; c < 4; ++c) {                                             \
      const int off = w * 4096 + c * 1024;                                    \
      load_lds16(srcB + koff + off + lane * 16, bB + off);                    \
    }                                                                         \
  }

  STAGE(0, 0);
  __syncthreads();

  for (int kt = 0; kt < KITERS; ++kt) {
    const int cur = kt & 1;
    if (kt + 1 < KITERS) STAGE(kt + 1, cur ^ 1);

    const unsigned char* bA = lds + cur * 32768;
    const unsigned char* bB = bA + 16384;
    bf16x8 afrag[2][4], bfrag[2][4];
#pragma unroll
    for (int h = 0; h < 2; ++h)
#pragma unroll
      for (int i = 0; i < 4; ++i) {
        afrag[h][i] = *(const bf16x8*)(bA + (kg + 4 * h) * 2048 + (wm * 64 + i * 16 + lrow) * 16);
        bfrag[h][i] = *(const bf16x8*)(bB + (kg + 4 * h) * 2048 + (wn * 64 + i * 16 + lrow) * 16);
      }
#pragma unroll
    for (int i = 0; i < 4; ++i)
#pragma unroll
      for (int j = 0; j < 4; ++j) {
        acc[i][j] = __builtin_amdgcn_mfma_f32_16x16x32_bf16(afrag[0][i], bfrag[0][j], acc[i][j], 0, 0, 0);
        acc[i][j] = __builtin_amdgcn_mfma_f32_16x16x32_bf16(afrag[1][i], bfrag[1][j], acc[i][j], 0, 0, 0);
      }
    __syncthreads();   // drains vmcnt(0): next-tile loads retired + LDS reads done
  }

  // winv from partial sums (LDS free now)
  float* winv = (float*)lds;
  if (t < 128) {
    float s = 0.f;
#pragma unroll
    for (int k = 0; k < 8; ++k) s += partial[(size_t)k * NT128 + n0 + t];
    winv[t] = 1.f / fmaxf(sqrtf(s), 1e-8f);
  }
  __syncthreads();

  // epilogue: C layout col=lane&15, row=(lane>>4)*4+reg
#pragma unroll
  for (int j = 0; j < 4; ++j) {
    const int cl = wn * 64 + j * 16 + lrow;
    const int col = n0 + cl;
    if (col < CK) {
      const float wv = winv[cl];
#pragma unroll
      for (int i = 0; i < 4; ++i) {
#pragma unroll
        for (int jj = 0; jj < 4; ++jj) {
          const int row = mtile * BM + wm * 64 + i * 16 + kg * 4 + jj;
          out[(size_t)row * CK + col] = acc[i][j][jj] * wv;
        }
      }
    }
  }
}

extern "C" void kernel_launch(void* const* d_in, const int* in_sizes, int n_in,
                              void* d_out, int out_size, void* d_ws, size_t ws_size,
                              hipStream_t stream) {
  const float* x = (const float*)d_in[0];
  const float* W = (const float*)d_in[1];
  float* out = (float*)d_out;
  const int Bn = in_sizes[0] / D_DIM;     // 512
  const int CK = in_sizes[1] / D_DIM;     // 17982
  const int ntiles = (CK + BN - 1) / BN;  // 141
  const int mtiles = Bn / BM;             // 4
  const int NT128 = ntiles * BN;          // 18048

  unsigned char* ws = (unsigned char*)d_ws;
  float* partial = (float*)ws;                                  // 8*NT128*4 = 577536 B
  unsigned short* An = (unsigned short*)(ws + 8 * (size_t)NT128 * 4);
  unsigned short* Wt = (unsigned short*)(ws + 8 * (size_t)NT128 * 4 + (size_t)mtiles * TILE_BYTES);

  const int nWtBlocks = ntiles * 8;
  const int nXBlocks = Bn / 4;            // 128
  hipLaunchKernelGGL(prep_kernel, dim3(nWtBlocks + nXBlocks), dim3(256), 0, stream,
                     x, W, An, Wt, partial, CK, NT128, nWtBlocks);
  hipLaunchKernelGGL(gemm_kernel, dim3(ntiles * mtiles), dim3(256), 0, stream,
                     An, Wt, partial, out, CK, NT128);
}